// Round 1
// 398.910 us; speedup vs baseline: 1.0132x; 1.0132x over previous
//
#include <hip/hip_runtime.h>

// Fused 7-layer 1x1-conv chain, round 4: barrier-free wave-local staging.
//  - Each wave owns 32 px; stages [128 ch][32 px] fp32 into its private 16 KiB LDS
//    region with 16x global_load_lds (16B/lane), ALL issued up front.
//  - Main loop gated by counted s_waitcnt vmcnt(12/8/4/0) — no __syncthreads, no
//    vmcnt(0) drain until the last chunk (T3/T4 pattern). Weight A-frag loads are
//    issued BEFORE stage instrs 4..15 so their conversion waits don't force stage
//    retirement (vmcnt retires in order).
//  - px XOR-swizzle (px ^ 8*((ch>>3)&3)) applied via pre-swizzled GLOBAL source
//    (global_load_lds dest must stay lane-linear): L1 B-frag ds_read conflicts
//    4-way -> 2-way (free).
//  - fp32->bf16 via scalar __bf16 casts (compiler emits v_cvt_pk_bf16_f32) instead
//    of ~10-op manual RNE; leaky = fmaxf(v, 0.01f*v) (2 ops).
//  - x-region is dead after L1 -> h1/h2/h3 epilogue scratch reuses it (per-wave,
//    in-order DS). LDS total 64.7 KiB -> 2 blocks/CU.
//
// MFMA 16x16x32 layouts: A[m][k]: m=lane&15, k=(lane>>4)*8+j
//                        B[k][n]: n=lane&15, k=(lane>>4)*8+j
//                        C/D: col=lane&15, row=(lane>>4)*4+reg

#define NEG_SLOPE 0.01f
constexpr int HW = 65536;  // 256*256

typedef __attribute__((ext_vector_type(8))) short bf16x8;
typedef __attribute__((ext_vector_type(4))) float f32x4;
typedef __attribute__((ext_vector_type(2))) float f32x2;

__device__ __forceinline__ float leaky(float v) { return fmaxf(v, v * NEG_SLOPE); }

// fp32 pair -> packed bf16x2. Scalar __bf16 casts: compiler fuses to
// v_cvt_pk_bf16_f32 on gfx950 (m240: do NOT hand-write the asm).
__device__ __forceinline__ unsigned pk2(float a, float b) {
    __bf16 ba = (__bf16)a, bb = (__bf16)b;
    unsigned short ua = __builtin_bit_cast(unsigned short, ba);
    unsigned short ub = __builtin_bit_cast(unsigned short, bb);
    return (unsigned)ua | ((unsigned)ub << 16);
}

// A-frag from o-major fp32 weight matrix W[m][k] (row length C); k 8-aligned
__device__ __forceinline__ bf16x8 loadA(const float* __restrict__ wsrc, int C, int m, int k) {
    f32x4 lo = *(const f32x4*)(wsrc + m * C + k);
    f32x4 hi = *(const f32x4*)(wsrc + m * C + k + 4);
    union { bf16x8 v; unsigned u[4]; } r;
    r.u[0] = pk2(lo[0], lo[1]); r.u[1] = pk2(lo[2], lo[3]);
    r.u[2] = pk2(hi[0], hi[1]); r.u[3] = pk2(hi[2], hi[3]);
    return r.v;
}

__device__ __forceinline__ void async_cp16(const float* g, float* l) {
    __builtin_amdgcn_global_load_lds((const __attribute__((address_space(1))) unsigned*)g,
                                     (__attribute__((address_space(3))) unsigned*)l,
                                     16, 0, 0);
}

// compiler-level memory fence (0 instructions): stops TBAA cross-type reordering
// between the x-tile float reads/writes and the short/uint2 epilogue scratch.
__device__ __forceinline__ void cfence() { asm volatile("" ::: "memory"); }

__global__ __launch_bounds__(256, 2) void fused_wavepipe_kernel(
    const float* __restrict__ x,
    const float* __restrict__ w1, const float* __restrict__ w2,
    const float* __restrict__ w3, const float* __restrict__ w4,
    const float* __restrict__ w5, const float* __restrict__ w6,
    const float* __restrict__ w7, float* __restrict__ out) {
    __shared__ float lds_x[4][4096];  // per-wave [128 ch][32 px] fp32 (px swizzled); reused as h-scratch
    __shared__ float lds_tw[176];     // tail weights w4|w5|w6|w7

    const int tid = threadIdx.x;
    if (tid < 128)      lds_tw[tid] = w4[tid];
    else if (tid < 160) lds_tw[tid] = w5[tid - 128];
    else if (tid < 168) lds_tw[tid] = w6[tid - 160];
    else if (tid < 170) lds_tw[tid] = w7[tid - 168];

    const int w    = tid >> 6;
    const int lane = tid & 63;
    const int n    = lane & 15;   // frag minor index
    const int q    = lane >> 4;   // quad
    const int pl   = lane & 31;

    const int px0   = blockIdx.x * 128;  // block's 128 contiguous pixels (batch-uniform)
    const int batch = px0 >> 16;
    const int pin   = px0 & (HW - 1);
    const float* xg = x + (size_t)batch * 128 * HW + pin + w * 32;  // this wave's 32-px column

    float* Xw = &lds_x[w][0];

    __syncthreads();  // lds_tw visible; only the tw loads are in flight here

    // ---- staging geometry ----
    // instruction i (0..15): channels i*8 .. i*8+7 of this wave's 32-px column.
    //   q8 = (i&3)*8 is the read-side swizzle group of those channels.
    //   lane: r = lane>>3 (channel row within instr), s4 = (lane&7)*4 (4-px slot).
    //   LDS dest lane-linear: Xw + i*256 + r*32 + s4  (= base + lane*16B).
    //   Global src pre-swizzled: px slot s4 ^ q8  (so LDS[ch][u] = x[ch][u ^ q8]).
    const int r  = lane >> 3;
    const int s4 = (lane & 7) * 4;
    const float* xgr = xg + (size_t)r * HW;

    // chunk 0 (instrs 0..3) first — in flight under the weight-conversion phase
#pragma unroll
    for (int i = 0; i < 4; ++i)
        async_cp16(xgr + (size_t)(i * 8) * HW + (s4 ^ ((i & 3) * 8)), Xw + i * 256);
    cfence();
    __builtin_amdgcn_sched_barrier(0);

    // ---- weight A-frags into VGPRs (loads issued BEFORE stage instrs 4..15) ----
    bf16x8 a1[4][4];  // L1: M=64 (4 Mt) x K=128 (4 kc)
#pragma unroll
    for (int Mt = 0; Mt < 4; ++Mt)
#pragma unroll
        for (int kc = 0; kc < 4; ++kc)
            a1[Mt][kc] = loadA(w1, 128, Mt * 16 + n, kc * 32 + q * 8);
    bf16x8 a2[2][2];  // L2: M=32 x K=64
#pragma unroll
    for (int Mt = 0; Mt < 2; ++Mt)
#pragma unroll
        for (int kc = 0; kc < 2; ++kc)
            a2[Mt][kc] = loadA(w2, 64, Mt * 16 + n, kc * 32 + q * 8);
    bf16x8 a3 = loadA(w3, 32, n, q * 8);  // L3: M=16 x K=32
    cfence();
    __builtin_amdgcn_sched_barrier(0);

    // chunks 1..3 (instrs 4..15) — all in flight across the whole L1 loop
#pragma unroll
    for (int i = 4; i < 16; ++i)
        async_cp16(xgr + (size_t)(i * 8) * HW + (s4 ^ ((i & 3) * 8)), Xw + i * 256);
    cfence();
    __builtin_amdgcn_sched_barrier(0);

    // ---- L1 main loop: counted vmcnt gates, no barriers ----
    f32x4 acc1[4][2];
#pragma unroll
    for (int Mt = 0; Mt < 4; ++Mt)
#pragma unroll
        for (int Nt = 0; Nt < 2; ++Nt) acc1[Mt][Nt] = (f32x4){0.f, 0.f, 0.f, 0.f};

    const int pq = q * 8;
#pragma unroll
    for (int kc = 0; kc < 4; ++kc) {
        // chunk kc staged by instrs 4kc..4kc+3 -> wait until <= 12-4kc outstanding
        if      (kc == 0) asm volatile("s_waitcnt vmcnt(12)" ::: "memory");
        else if (kc == 1) asm volatile("s_waitcnt vmcnt(8)"  ::: "memory");
        else if (kc == 2) asm volatile("s_waitcnt vmcnt(4)"  ::: "memory");
        else              asm volatile("s_waitcnt vmcnt(0)"  ::: "memory");
        __builtin_amdgcn_sched_barrier(0);
        const float* xb = Xw + kc * 1024;
#pragma unroll
        for (int Nt = 0; Nt < 2; ++Nt) {
            const int pxsw = (Nt * 16 + n) ^ pq;  // swizzled px slot (2-way banks = free)
            float t[8];
#pragma unroll
            for (int j = 0; j < 8; ++j)
                t[j] = xb[(pq + j) * 32 + pxsw];
            union { bf16x8 v; unsigned u[4]; } b;
            b.u[0] = pk2(t[0], t[1]); b.u[1] = pk2(t[2], t[3]);
            b.u[2] = pk2(t[4], t[5]); b.u[3] = pk2(t[6], t[7]);
#pragma unroll
            for (int Mt = 0; Mt < 4; ++Mt)
                acc1[Mt][Nt] = __builtin_amdgcn_mfma_f32_16x16x32_bf16(a1[Mt][kc], b.v, acc1[Mt][Nt], 0, 0, 0);
        }
    }
    cfence();  // x-region dead; safe to overwrite as h1 (per-wave in-order DS)

    // ---- epilogue (all intra-wave; per-wave DS ops are in-order => no barriers) ----
    short* h1 = (short*)Xw;  // [32 px][64 ch] stride 68 shorts
#pragma unroll
    for (int Mt = 0; Mt < 4; ++Mt)
#pragma unroll
        for (int Nt = 0; Nt < 2; ++Nt) {
            int px = Nt * 16 + n;
            uint2 v;
            v.x = pk2(leaky(acc1[Mt][Nt][0]), leaky(acc1[Mt][Nt][1]));
            v.y = pk2(leaky(acc1[Mt][Nt][2]), leaky(acc1[Mt][Nt][3]));
            *(uint2*)(h1 + px * 68 + Mt * 16 + q * 4) = v;  // 8B-aligned
        }
    cfence();

    f32x4 acc2[2][2];
#pragma unroll
    for (int Mt = 0; Mt < 2; ++Mt)
#pragma unroll
        for (int Nt = 0; Nt < 2; ++Nt) acc2[Mt][Nt] = (f32x4){0.f, 0.f, 0.f, 0.f};
#pragma unroll
    for (int Nt = 0; Nt < 2; ++Nt)
#pragma unroll
        for (int kc = 0; kc < 2; ++kc) {
            int off = (Nt * 16 + n) * 68 + kc * 32 + q * 8;
            uint2 lo = *(const uint2*)(h1 + off);
            uint2 hi = *(const uint2*)(h1 + off + 4);
            union { bf16x8 v; unsigned u[4]; } b;
            b.u[0] = lo.x; b.u[1] = lo.y; b.u[2] = hi.x; b.u[3] = hi.y;
#pragma unroll
            for (int Mt = 0; Mt < 2; ++Mt)
                acc2[Mt][Nt] = __builtin_amdgcn_mfma_f32_16x16x32_bf16(a2[Mt][kc], b.v, acc2[Mt][Nt], 0, 0, 0);
        }
    cfence();

    short* h2 = (short*)Xw;  // [32 px][32 ch] stride 36 shorts (reuse; in-order DS)
#pragma unroll
    for (int Mt = 0; Mt < 2; ++Mt)
#pragma unroll
        for (int Nt = 0; Nt < 2; ++Nt) {
            int px = Nt * 16 + n;
            uint2 v;
            v.x = pk2(leaky(acc2[Mt][Nt][0]), leaky(acc2[Mt][Nt][1]));
            v.y = pk2(leaky(acc2[Mt][Nt][2]), leaky(acc2[Mt][Nt][3]));
            *(uint2*)(h2 + px * 36 + Mt * 16 + q * 4) = v;
        }
    cfence();

    f32x4 acc3[2];
#pragma unroll
    for (int Nt = 0; Nt < 2; ++Nt) {
        int off = (Nt * 16 + n) * 36 + q * 8;
        uint2 lo = *(const uint2*)(h2 + off);
        uint2 hi = *(const uint2*)(h2 + off + 4);
        union { bf16x8 v; unsigned u[4]; } b;
        b.u[0] = lo.x; b.u[1] = lo.y; b.u[2] = hi.x; b.u[3] = hi.y;
        f32x4 zero = {0.f, 0.f, 0.f, 0.f};
        acc3[Nt] = __builtin_amdgcn_mfma_f32_16x16x32_bf16(a3, b.v, zero, 0, 0, 0);
    }
    cfence();

    float* h3 = (float*)Xw;  // [32 px][16 ch] stride 18 floats
#pragma unroll
    for (int Nt = 0; Nt < 2; ++Nt) {
        int px = Nt * 16 + n;
        f32x2 va = {leaky(acc3[Nt][0]), leaky(acc3[Nt][1])};
        f32x2 vb = {leaky(acc3[Nt][2]), leaky(acc3[Nt][3])};
        *(f32x2*)(h3 + px * 18 + q * 4)     = va;
        *(f32x2*)(h3 + px * 18 + q * 4 + 2) = vb;
    }
    cfence();

    // ---- tail L4-L7, one px per lane (halves duplicate; lower half stores) ----
    float hh[16];
#pragma unroll
    for (int c = 0; c < 16; ++c) hh[c] = h3[pl * 18 + c];

    float g4[8];
#pragma unroll
    for (int o = 0; o < 8; ++o) {
        float a = 0.f;
#pragma unroll
        for (int c = 0; c < 16; ++c) a = fmaf(lds_tw[o * 16 + c], hh[c], a);
        g4[o] = leaky(a);
    }
    float g5[4];
#pragma unroll
    for (int o = 0; o < 4; ++o) {
        float a = 0.f;
#pragma unroll
        for (int c = 0; c < 8; ++c) a = fmaf(lds_tw[128 + o * 8 + c], g4[c], a);
        g5[o] = leaky(a);
    }
    float g6[2];
#pragma unroll
    for (int o = 0; o < 2; ++o) {
        float a = 0.f;
#pragma unroll
        for (int c = 0; c < 4; ++c) a = fmaf(lds_tw[160 + o * 4 + c], g5[c], a);
        g6[o] = leaky(a);
    }
    float res = fmaf(lds_tw[168], g6[0], lds_tw[169] * g6[1]);
    if (lane < 32) out[px0 + w * 32 + pl] = res;
}

extern "C" void kernel_launch(void* const* d_in, const int* in_sizes, int n_in,
                              void* d_out, int out_size, void* d_ws, size_t ws_size,
                              hipStream_t stream) {
    const float* x  = (const float*)d_in[0];
    const float* w1 = (const float*)d_in[1];
    const float* w2 = (const float*)d_in[2];
    const float* w3 = (const float*)d_in[3];
    const float* w4 = (const float*)d_in[4];
    const float* w5 = (const float*)d_in[5];
    const float* w6 = (const float*)d_in[6];
    const float* w7 = (const float*)d_in[7];
    float* out = (float*)d_out;

    const int P = 8 * 256 * 256;
    fused_wavepipe_kernel<<<P / 128, 256, 0, stream>>>(x, w1, w2, w3, w4, w5, w6, w7, out);
}

// Round 2
// 380.151 us; speedup vs baseline: 1.0632x; 1.0493x over previous
//
#include <hip/hip_runtime.h>

// Fused 7-layer 1x1-conv chain, round 5: persistent pipelined blocks.
//  - Grid = 512 blocks (exactly 2 resident/CU, no relaunch); each block owns one
//    128-px column (pin = b*128) and loops over all 8 batches (TPB=8 tiles,
//    x stride 32 MiB/tile). Weights loaded+converted ONCE per block.
//  - Per wave: rolling distance-2 chunk ring (2 x 4 KiB LDS bufs). While computing
//    chunk c, issue global_load_lds for chunk c+2 (crosses tile boundary, so the
//    next tile's first chunks are in flight during the whole L2-L7 epilogue).
//    Issue MUST come after the full Nt loop: chunk c+2 overwrites the buffer
//    chunk c was just read from (ring-2).
//  - Gating: uniform s_waitcnt vmcnt(4) per chunk. Audited in-order-retirement
//    composition at each wait (stage quads + 1 out-store/tile): never under-waits;
//    only the last chunk of the last tile needs vmcnt(0). No __syncthreads after
//    the one-time tw barrier; all LDS is wave-private.
//  - px XOR-swizzle (LDS[ch][u] = x[ch][u ^ 8*(chgrp&3)]) via pre-swizzled GLOBAL
//    source (global_load_lds dest stays lane-linear): L1 B-frag ds_read 4-way -> 2-way.
//  - Epilogue scratch is a separate 4.25 KiB/wave region (x-bufs hold in-flight
//    data during epilogue). LDS total 50.9 KiB -> 2 blocks/CU with headroom.
//
// MFMA 16x16x32 layouts: A[m][k]: m=lane&15, k=(lane>>4)*8+j
//                        B[k][n]: n=lane&15, k=(lane>>4)*8+j
//                        C/D: col=lane&15, row=(lane>>4)*4+reg

#define NEG_SLOPE 0.01f
constexpr int HW = 65536;                     // 256*256
constexpr int GRID = 512;                     // 2 blocks/CU exactly
constexpr int TPB  = 8;                       // tiles per block (= batch count)
constexpr size_t TSTRIDE = (size_t)128 * HW;  // floats between a block's tiles

typedef __attribute__((ext_vector_type(8))) short bf16x8;
typedef __attribute__((ext_vector_type(4))) float f32x4;
typedef __attribute__((ext_vector_type(2))) float f32x2;

__device__ __forceinline__ float leaky(float v) { return fmaxf(v, v * NEG_SLOPE); }

// fp32 pair -> packed bf16x2 (compiler emits v_cvt_pk_bf16_f32; m240: no hand asm)
__device__ __forceinline__ unsigned pk2(float a, float b) {
    __bf16 ba = (__bf16)a, bb = (__bf16)b;
    unsigned short ua = __builtin_bit_cast(unsigned short, ba);
    unsigned short ub = __builtin_bit_cast(unsigned short, bb);
    return (unsigned)ua | ((unsigned)ub << 16);
}

// A-frag from o-major fp32 weight matrix W[m][k] (row length C); k 8-aligned
__device__ __forceinline__ bf16x8 loadA(const float* __restrict__ wsrc, int C, int m, int k) {
    f32x4 lo = *(const f32x4*)(wsrc + m * C + k);
    f32x4 hi = *(const f32x4*)(wsrc + m * C + k + 4);
    union { bf16x8 v; unsigned u[4]; } r;
    r.u[0] = pk2(lo[0], lo[1]); r.u[1] = pk2(lo[2], lo[3]);
    r.u[2] = pk2(hi[0], hi[1]); r.u[3] = pk2(hi[2], hi[3]);
    return r.v;
}

__device__ __forceinline__ void async_cp16(const float* g, float* l) {
    __builtin_amdgcn_global_load_lds((const __attribute__((address_space(1))) unsigned*)g,
                                     (__attribute__((address_space(3))) unsigned*)l,
                                     16, 0, 0);
}

// 0-instruction compiler memory fence (stops TBAA cross-type reordering)
__device__ __forceinline__ void cfence() { asm volatile("" ::: "memory"); }

__global__ __launch_bounds__(256, 2) void fused_persist_kernel(
    const float* __restrict__ x,
    const float* __restrict__ w1, const float* __restrict__ w2,
    const float* __restrict__ w3, const float* __restrict__ w4,
    const float* __restrict__ w5, const float* __restrict__ w6,
    const float* __restrict__ w7, float* __restrict__ out) {
    __shared__ float lds_x[4][2][1024];  // per-wave ring: 2 bufs x [32 ch][32 px] fp32 (px swizzled)
    __shared__ float lds_s[4][1088];     // per-wave epilogue scratch h1/h2/h3 (4352 B)
    __shared__ float lds_tw[176];        // tail weights w4|w5|w6|w7

    const int tid = threadIdx.x;
    if (tid < 128)      lds_tw[tid] = w4[tid];
    else if (tid < 160) lds_tw[tid] = w5[tid - 128];
    else if (tid < 168) lds_tw[tid] = w6[tid - 160];
    else if (tid < 170) lds_tw[tid] = w7[tid - 168];

    const int w    = tid >> 6;
    const int lane = tid & 63;
    const int n    = lane & 15;   // frag minor index
    const int q    = lane >> 4;   // quad
    const int pl   = lane & 31;
    const int r    = lane >> 3;   // stage: channel row within instr
    const int s4   = (lane & 7) * 4;  // stage: 4-px slot

    const int b = blockIdx.x;
    // tile it: px0 = (b + it*GRID)*128 = b*128 + it*65536 -> batch=it, pin=b*128
    const float* xg = x + b * 128 + w * 32;  // + it*TSTRIDE + ch*HW

    __syncthreads();  // lds_tw visible (drains tw loads; before any counted VMEM)

    // ---- weights once per block: 42 dwordx4 loads, retire before stage chunk 0 ----
    bf16x8 a1[4][4];  // L1: M=64 (4 Mt) x K=128 (4 kc)
#pragma unroll
    for (int Mt = 0; Mt < 4; ++Mt)
#pragma unroll
        for (int kc = 0; kc < 4; ++kc)
            a1[Mt][kc] = loadA(w1, 128, Mt * 16 + n, kc * 32 + q * 8);
    bf16x8 a2[2][2];  // L2: M=32 x K=64
#pragma unroll
    for (int Mt = 0; Mt < 2; ++Mt)
#pragma unroll
        for (int kc = 0; kc < 2; ++kc)
            a2[Mt][kc] = loadA(w2, 64, Mt * 16 + n, kc * 32 + q * 8);
    bf16x8 a3 = loadA(w3, 32, n, q * 8);  // L3: M=16 x K=32
    cfence();
    __builtin_amdgcn_sched_barrier(0);

    // stage chunk KCX (32 ch x 32 px) of tile based at BASE into ring buf KCX&1.
    // instr i_: channels KCX*32 + i_*8 + r; LDS dest lane-linear (base + lane*16B);
    // global px slot pre-swizzled s4 ^ (i_*8) so LDS[ch][u] = x[ch][u ^ 8*chgrp].
#define STAGE(BASE, KCX) do {                                                        \
        const float* gb_ = (BASE) + (size_t)((KCX) * 32 + r) * HW;                   \
        float* lb_ = &lds_x[w][(KCX) & 1][0];                                        \
        _Pragma("unroll")                                                            \
        for (int i_ = 0; i_ < 4; ++i_)                                               \
            async_cp16(gb_ + (size_t)(i_ * 8) * HW + (s4 ^ (i_ * 8)), lb_ + i_ * 256); \
    } while (0)

    // prologue: chunks 0,1 of tile 0 in flight
    STAGE(xg, 0);
    STAGE(xg, 1);
    cfence();

    const int pq = q * 8;
    for (int it = 0; it < TPB; ++it) {
        const float* xg_it = xg + (size_t)it * TSTRIDE;

        f32x4 acc1[4][2];
#pragma unroll
        for (int Mt = 0; Mt < 4; ++Mt)
#pragma unroll
            for (int Nt = 0; Nt < 2; ++Nt) acc1[Mt][Nt] = (f32x4){0.f, 0.f, 0.f, 0.f};

#pragma unroll
        for (int kc = 0; kc < 4; ++kc) {
            // wait for chunk 4*it+kc. In-order retirement audit: ops issued after
            // this chunk's 4 stages are always >= 4 (next chunk's stages, +store),
            // except the very last chunk of the last tile -> vmcnt(0).
            if (kc == 3 && it == TPB - 1) asm volatile("s_waitcnt vmcnt(0)" ::: "memory");
            else                          asm volatile("s_waitcnt vmcnt(4)" ::: "memory");
            __builtin_amdgcn_sched_barrier(0);

            const float* xb = &lds_x[w][kc & 1][0];
#pragma unroll
            for (int Nt = 0; Nt < 2; ++Nt) {
                const int pxsw = (Nt * 16 + n) ^ pq;  // swizzled px slot (2-way banks = free)
                float t[8];
#pragma unroll
                for (int j = 0; j < 8; ++j)
                    t[j] = xb[(pq + j) * 32 + pxsw];
                union { bf16x8 v; unsigned u[4]; } bb;
                bb.u[0] = pk2(t[0], t[1]); bb.u[1] = pk2(t[2], t[3]);
                bb.u[2] = pk2(t[4], t[5]); bb.u[3] = pk2(t[6], t[7]);
#pragma unroll
                for (int Mt = 0; Mt < 4; ++Mt)
                    acc1[Mt][Nt] = __builtin_amdgcn_mfma_f32_16x16x32_bf16(a1[Mt][kc], bb.v, acc1[Mt][Nt], 0, 0, 0);
            }
            __builtin_amdgcn_sched_barrier(0);

            // issue chunk c+2 (same parity -> the buffer just consumed; all its
            // ds_reads are data-complete, DMA lands >=500cyc later: safe).
            if (kc < 2)            STAGE(xg_it, kc + 2);           // this tile, chunk kc+2
            else if (it < TPB - 1) STAGE(xg_it + TSTRIDE, kc - 2); // next tile, chunk kc-2
            cfence();
        }

        // ---- epilogue (wave-private scratch; per-wave DS in-order => no barriers) ----
        float* Sw = &lds_s[w][0];
        short* h1 = (short*)Sw;  // [32 px][64 ch] stride 68 shorts
#pragma unroll
        for (int Mt = 0; Mt < 4; ++Mt)
#pragma unroll
            for (int Nt = 0; Nt < 2; ++Nt) {
                int px = Nt * 16 + n;
                uint2 v;
                v.x = pk2(leaky(acc1[Mt][Nt][0]), leaky(acc1[Mt][Nt][1]));
                v.y = pk2(leaky(acc1[Mt][Nt][2]), leaky(acc1[Mt][Nt][3]));
                *(uint2*)(h1 + px * 68 + Mt * 16 + q * 4) = v;  // 8B-aligned
            }
        cfence();

        f32x4 acc2[2][2];
#pragma unroll
        for (int Mt = 0; Mt < 2; ++Mt)
#pragma unroll
            for (int Nt = 0; Nt < 2; ++Nt) acc2[Mt][Nt] = (f32x4){0.f, 0.f, 0.f, 0.f};
#pragma unroll
        for (int Nt = 0; Nt < 2; ++Nt)
#pragma unroll
            for (int kc = 0; kc < 2; ++kc) {
                int off = (Nt * 16 + n) * 68 + kc * 32 + q * 8;
                uint2 lo = *(const uint2*)(h1 + off);
                uint2 hi = *(const uint2*)(h1 + off + 4);
                union { bf16x8 v; unsigned u[4]; } bb;
                bb.u[0] = lo.x; bb.u[1] = lo.y; bb.u[2] = hi.x; bb.u[3] = hi.y;
#pragma unroll
                for (int Mt = 0; Mt < 2; ++Mt)
                    acc2[Mt][Nt] = __builtin_amdgcn_mfma_f32_16x16x32_bf16(a2[Mt][kc], bb.v, acc2[Mt][Nt], 0, 0, 0);
            }
        cfence();

        short* h2 = (short*)Sw;  // [32 px][32 ch] stride 36 shorts
#pragma unroll
        for (int Mt = 0; Mt < 2; ++Mt)
#pragma unroll
            for (int Nt = 0; Nt < 2; ++Nt) {
                int px = Nt * 16 + n;
                uint2 v;
                v.x = pk2(leaky(acc2[Mt][Nt][0]), leaky(acc2[Mt][Nt][1]));
                v.y = pk2(leaky(acc2[Mt][Nt][2]), leaky(acc2[Mt][Nt][3]));
                *(uint2*)(h2 + px * 36 + Mt * 16 + q * 4) = v;
            }
        cfence();

        f32x4 acc3[2];
#pragma unroll
        for (int Nt = 0; Nt < 2; ++Nt) {
            int off = (Nt * 16 + n) * 36 + q * 8;
            uint2 lo = *(const uint2*)(h2 + off);
            uint2 hi = *(const uint2*)(h2 + off + 4);
            union { bf16x8 v; unsigned u[4]; } bb;
            bb.u[0] = lo.x; bb.u[1] = lo.y; bb.u[2] = hi.x; bb.u[3] = hi.y;
            f32x4 zero = {0.f, 0.f, 0.f, 0.f};
            acc3[Nt] = __builtin_amdgcn_mfma_f32_16x16x32_bf16(a3, bb.v, zero, 0, 0, 0);
        }
        cfence();

        float* h3 = Sw;  // [32 px][16 ch] stride 18 floats
#pragma unroll
        for (int Nt = 0; Nt < 2; ++Nt) {
            int px = Nt * 16 + n;
            f32x2 va = {leaky(acc3[Nt][0]), leaky(acc3[Nt][1])};
            f32x2 vb = {leaky(acc3[Nt][2]), leaky(acc3[Nt][3])};
            *(f32x2*)(h3 + px * 18 + q * 4)     = va;
            *(f32x2*)(h3 + px * 18 + q * 4 + 2) = vb;
        }
        cfence();

        // ---- tail L4-L7, one px per lane (halves duplicate; lower half stores) ----
        float hh[16];
#pragma unroll
        for (int c = 0; c < 16; ++c) hh[c] = h3[pl * 18 + c];

        float g4[8];
#pragma unroll
        for (int o = 0; o < 8; ++o) {
            float a = 0.f;
#pragma unroll
            for (int c = 0; c < 16; ++c) a = fmaf(lds_tw[o * 16 + c], hh[c], a);
            g4[o] = leaky(a);
        }
        float g5[4];
#pragma unroll
        for (int o = 0; o < 4; ++o) {
            float a = 0.f;
#pragma unroll
            for (int c = 0; c < 8; ++c) a = fmaf(lds_tw[128 + o * 8 + c], g4[c], a);
            g5[o] = leaky(a);
        }
        float g6[2];
#pragma unroll
        for (int o = 0; o < 2; ++o) {
            float a = 0.f;
#pragma unroll
            for (int c = 0; c < 4; ++c) a = fmaf(lds_tw[160 + o * 4 + c], g5[c], a);
            g6[o] = leaky(a);
        }
        float res = fmaf(lds_tw[168], g6[0], lds_tw[169] * g6[1]);
        if (lane < 32) out[b * 128 + it * 65536 + w * 32 + pl] = res;  // 1 VMEM op (counted)
        cfence();
    }
#undef STAGE
}

extern "C" void kernel_launch(void* const* d_in, const int* in_sizes, int n_in,
                              void* d_out, int out_size, void* d_ws, size_t ws_size,
                              hipStream_t stream) {
    const float* x  = (const float*)d_in[0];
    const float* w1 = (const float*)d_in[1];
    const float* w2 = (const float*)d_in[2];
    const float* w3 = (const float*)d_in[3];
    const float* w4 = (const float*)d_in[4];
    const float* w5 = (const float*)d_in[5];
    const float* w6 = (const float*)d_in[6];
    const float* w7 = (const float*)d_in[7];
    float* out = (float*)d_out;

    fused_persist_kernel<<<GRID, 256, 0, stream>>>(x, w1, w2, w3, w4, w5, w6, w7, out);
}